// Round 2
// baseline (5463.175 us; speedup 1.0000x reference)
//
#include <hip/hip_runtime.h>

#define N_NODES 50000
#define N_EDGES 600000
#define HID 128
#define N_LAYERS 3
#define N_GRAPHS 64

// ---------------- h = x * node_imp ----------------
__global__ __launch_bounds__(256) void scale_kernel(const float* __restrict__ x,
                                                    const float* __restrict__ imp,
                                                    float* __restrict__ h) {
  int i = blockIdx.x * 256 + threadIdx.x;            // over N_NODES*32 float4
  if (i >= N_NODES * (HID / 4)) return;
  float s = imp[i >> 5];
  float4 v = reinterpret_cast<const float4*>(x)[i];
  v.x *= s; v.y *= s; v.z *= s; v.w *= s;
  reinterpret_cast<float4*>(h)[i] = v;
}

// ---------------- CSR build: histogram ----------------
__global__ __launch_bounds__(256) void hist_kernel(const int* __restrict__ dst,
                                                   int* __restrict__ deg) {
  int e = blockIdx.x * 256 + threadIdx.x;
  if (e < N_EDGES) atomicAdd(&deg[dst[e]], 1);
}

// ---------------- CSR build: exclusive scan (single block, 1024 thr) --------
// Each thread owns a contiguous 49-element chunk; wave shfl scan of chunk sums;
// 2 barriers total instead of Hillis-Steele's ~1000.
__global__ __launch_bounds__(1024) void scan_kernel(const int* __restrict__ deg,
                                                    int* __restrict__ rowptr,
                                                    int* __restrict__ cursor) {
  const int CHUNK = 49;                              // 1024*49 = 50176 >= N_NODES
  const int tid = threadIdx.x;
  const int lane = tid & 63;
  const int wid = tid >> 6;
  const int base = tid * CHUNK;
  int sum = 0;
#pragma unroll 1
  for (int i = 0; i < CHUNK; ++i) {
    int idx = base + i;
    if (idx < N_NODES) sum += deg[idx];
  }
  // wave-inclusive scan of per-thread sums
  int incl = sum;
#pragma unroll
  for (int off = 1; off < 64; off <<= 1) {
    int t = __shfl_up(incl, off, 64);
    if (lane >= off) incl += t;
  }
  __shared__ int wsum[16];
  __shared__ int wpre[16];
  if (lane == 63) wsum[wid] = incl;
  __syncthreads();
  if (tid == 0) {
    int c = 0;
#pragma unroll
    for (int i = 0; i < 16; ++i) { wpre[i] = c; c += wsum[i]; }
  }
  __syncthreads();
  int run = wpre[wid] + incl - sum;                  // block-exclusive prefix
  if (tid == 0) rowptr[0] = 0;
#pragma unroll 1
  for (int i = 0; i < CHUNK; ++i) {
    int idx = base + i;
    if (idx < N_NODES) {
      int v = deg[idx];
      cursor[idx] = run;
      run += v;
      rowptr[idx + 1] = run;
    }
  }
}

// ---------------- CSR build: scatter edge sources by dst ----------------
__global__ __launch_bounds__(256) void scatter_kernel(const int* __restrict__ src,
                                                      const int* __restrict__ dst,
                                                      int* __restrict__ cursor,
                                                      int* __restrict__ esrc) {
  int e = blockIdx.x * 256 + threadIdx.x;
  if (e >= N_EDGES) return;
  int pos = atomicAdd(&cursor[dst[e]], 1);
  esrc[pos] = src[e];
}

// ---------------- z = h + sum_{j->i} h[j]  (one wave per node) --------------
__global__ __launch_bounds__(256) void aggr_kernel(const float* __restrict__ h,
                                                   const int* __restrict__ rowptr,
                                                   const int* __restrict__ esrc,
                                                   float* __restrict__ z) {
  int wid = (blockIdx.x * 256 + threadIdx.x) >> 6;   // node id, 1 wave each
  if (wid >= N_NODES) return;
  int lane = threadIdx.x & 63;
  const float2* h2 = reinterpret_cast<const float2*>(h);
  float2 acc = h2[(size_t)wid * 64 + lane];          // self term (eps = 0)
  float2 acc2 = make_float2(0.f, 0.f);
  int s = rowptr[wid], e = rowptr[wid + 1];
  int j = s;
  for (; j + 2 <= e; j += 2) {                       // 2-way MLP unroll
    int s0 = esrc[j], s1 = esrc[j + 1];
    float2 v0 = h2[(size_t)s0 * 64 + lane];
    float2 v1 = h2[(size_t)s1 * 64 + lane];
    acc.x += v0.x; acc.y += v0.y;
    acc2.x += v1.x; acc2.y += v1.y;
  }
  if (j < e) {
    float2 v = h2[(size_t)esrc[j] * 64 + lane];
    acc.x += v.x; acc.y += v.y;
  }
  acc.x += acc2.x; acc.y += acc2.y;
  reinterpret_cast<float2*>(z)[(size_t)wid * 64 + lane] = acc;
}

// ---------------- fused MLP + h-update + pool ----------------
// h = relu( relu(z@W1+b1)@W2 + b2 ) * imp ; out[batch[i], lofs:lofs+128] += h
// 1024 thr (16 waves/CU, 4/SIMD): thread = (rg 0..31) x (fg 0..31),
// 1 row x 4 cols each, 32-row chunks.
// LDS: W1 64KB + W2 64KB + 32-row tile 16KB = 144KB -> 1 block/CU.
// Pool: batch sorted -> most chunks single-graph -> LDS tree-reduce then
// 128 atomics/chunk (was 4096).
__global__ __launch_bounds__(1024) void mlp_pool_kernel(
    const float* __restrict__ z, const float* __restrict__ W1,
    const float* __restrict__ b1, const float* __restrict__ W2,
    const float* __restrict__ b2, const float* __restrict__ imp,
    const int* __restrict__ batch, float* __restrict__ h,
    float* __restrict__ out, int lofs) {
  __shared__ float W1s[HID * HID];
  __shared__ float W2s[HID * HID];
  __shared__ float zs[32 * HID];                     // z tile / t tile / reduce scratch

  const int tid = threadIdx.x;
  {
    const float4* a = reinterpret_cast<const float4*>(W1);
    const float4* b = reinterpret_cast<const float4*>(W2);
    float4* sa = reinterpret_cast<float4*>(W1s);
    float4* sb = reinterpret_cast<float4*>(W2s);
#pragma unroll
    for (int i = 0; i < 4; ++i) {
      sa[tid + i * 1024] = a[tid + i * 1024];
      sb[tid + i * 1024] = b[tid + i * 1024];
    }
  }
  const int fg = tid & 31;                           // cols fg*4 .. fg*4+3
  const int rg = tid >> 5;                           // row within chunk
  const float4 bias1 = reinterpret_cast<const float4*>(b1)[fg];
  const float4 bias2 = reinterpret_cast<const float4*>(b2)[fg];
  __syncthreads();

  const int nchunks = (N_NODES + 31) >> 5;
  for (int c = blockIdx.x; c < nchunks; c += gridDim.x) {
    const int row0 = c << 5;
    const int row = row0 + rg;
    {  // stage 32 rows of z (1 float4 per thread, coalesced)
      float4 v = make_float4(0.f, 0.f, 0.f, 0.f);
      if (row < N_NODES) v = reinterpret_cast<const float4*>(z)[(size_t)row * 32 + fg];
      reinterpret_cast<float4*>(zs)[tid] = v;
    }
    __syncthreads();

    // ---- GEMM1: acc = z @ W1 + b1 ----
    float4 acc = bias1;
    {
      const float4* Wv = reinterpret_cast<const float4*>(W1s);
      const float4* zv = reinterpret_cast<const float4*>(zs);
#pragma unroll
      for (int k4 = 0; k4 < 32; ++k4) {
        float4 zq = zv[rg * 32 + k4];                // broadcast within half-wave
        float4 w0 = Wv[(4 * k4 + 0) * 32 + fg];
        float4 w1 = Wv[(4 * k4 + 1) * 32 + fg];
        float4 w2 = Wv[(4 * k4 + 2) * 32 + fg];
        float4 w3 = Wv[(4 * k4 + 3) * 32 + fg];
        acc.x += zq.x * w0.x + zq.y * w1.x + zq.z * w2.x + zq.w * w3.x;
        acc.y += zq.x * w0.y + zq.y * w1.y + zq.z * w2.y + zq.w * w3.y;
        acc.z += zq.x * w0.z + zq.y * w1.z + zq.z * w2.z + zq.w * w3.z;
        acc.w += zq.x * w0.w + zq.y * w1.w + zq.z * w2.w + zq.w * w3.w;
      }
    }
    __syncthreads();                                 // zs reads done

    {  // t = relu(acc) into zs
      float4 t;
      t.x = fmaxf(acc.x, 0.f); t.y = fmaxf(acc.y, 0.f);
      t.z = fmaxf(acc.z, 0.f); t.w = fmaxf(acc.w, 0.f);
      reinterpret_cast<float4*>(zs)[tid] = t;
    }
    __syncthreads();

    // ---- GEMM2: o_ = t @ W2 + b2 ----
    float4 o_ = bias2;
    {
      const float4* Wv = reinterpret_cast<const float4*>(W2s);
      const float4* tv = reinterpret_cast<const float4*>(zs);
#pragma unroll
      for (int k4 = 0; k4 < 32; ++k4) {
        float4 tq = tv[rg * 32 + k4];
        float4 w0 = Wv[(4 * k4 + 0) * 32 + fg];
        float4 w1 = Wv[(4 * k4 + 1) * 32 + fg];
        float4 w2 = Wv[(4 * k4 + 2) * 32 + fg];
        float4 w3 = Wv[(4 * k4 + 3) * 32 + fg];
        o_.x += tq.x * w0.x + tq.y * w1.x + tq.z * w2.x + tq.w * w3.x;
        o_.y += tq.x * w0.y + tq.y * w1.y + tq.z * w2.y + tq.w * w3.y;
        o_.z += tq.x * w0.z + tq.y * w1.z + tq.z * w2.z + tq.w * w3.z;
        o_.w += tq.x * w0.w + tq.y * w1.w + tq.z * w2.w + tq.w * w3.w;
      }
    }

    // ---- epilogue: h = relu(o_)*imp, write h, pool into out ----
    float si = (row < N_NODES) ? imp[row] : 0.f;     // si=0 -> hv=0 for pad rows
    float4 hv;
    hv.x = fmaxf(o_.x, 0.f) * si; hv.y = fmaxf(o_.y, 0.f) * si;
    hv.z = fmaxf(o_.z, 0.f) * si; hv.w = fmaxf(o_.w, 0.f) * si;
    if (row < N_NODES)
      reinterpret_cast<float4*>(h)[(size_t)row * 32 + fg] = hv;

    const int rlast = min(row0 + 31, N_NODES - 1);
    const int g0 = batch[row0];
    const bool uniform = (batch[rlast] == g0);       // block-uniform condition
    __syncthreads();                                 // all t reads done; zs free

    if (uniform) {
      // tree-reduce 32 rows in LDS, 1 atomic per output element per chunk
      float4 red = hv;
      reinterpret_cast<float4*>(zs)[tid] = hv;
      __syncthreads();
#pragma unroll
      for (int st = 16; st >= 1; st >>= 1) {
        if (rg < st) {
          float4 o = reinterpret_cast<const float4*>(zs)[(rg + st) * 32 + fg];
          red.x += o.x; red.y += o.y; red.z += o.z; red.w += o.w;
          if (st > 1) reinterpret_cast<float4*>(zs)[tid] = red;
        }
        __syncthreads();
      }
      if (rg == 0) {
        float* op = out + (size_t)g0 * (N_LAYERS * HID) + lofs + fg * 4;
        atomicAdd(op + 0, red.x); atomicAdd(op + 1, red.y);
        atomicAdd(op + 2, red.z); atomicAdd(op + 3, red.w);
      }
    } else {
      // graph-boundary chunk (~63 of 1563): per-row atomics
      if (row < N_NODES) {
        float* op = out + (size_t)batch[row] * (N_LAYERS * HID) + lofs + fg * 4;
        atomicAdd(op + 0, hv.x); atomicAdd(op + 1, hv.y);
        atomicAdd(op + 2, hv.z); atomicAdd(op + 3, hv.w);
      }
      // no barrier needed: zs untouched here; staging next iter only after
      // this thread passes its own stage+barrier
    }
  }
}

extern "C" void kernel_launch(void* const* d_in, const int* in_sizes, int n_in,
                              void* d_out, int out_size, void* d_ws, size_t ws_size,
                              hipStream_t stream) {
  const float* x    = (const float*)d_in[0];
  const int*   ei   = (const int*)d_in[1];          // [2, N_EDGES] (int32 via harness)
  const int*   batch= (const int*)d_in[2];
  const float* imp  = (const float*)d_in[3];
  const float* W1   = (const float*)d_in[4];        // [3,128,128]
  const float* b1   = (const float*)d_in[5];        // [3,128]
  const float* W2   = (const float*)d_in[6];
  const float* b2   = (const float*)d_in[7];
  float* out = (float*)d_out;                       // [64, 384]

  const int* src = ei;
  const int* dst = ei + N_EDGES;

  // workspace layout (16B-aligned floats first)
  char* w = (char*)d_ws;
  float* h = (float*)w;        w += (size_t)N_NODES * HID * sizeof(float);   // 25.6MB
  float* z = (float*)w;        w += (size_t)N_NODES * HID * sizeof(float);   // 25.6MB
  int* esrc   = (int*)w;       w += (size_t)N_EDGES * sizeof(int);           // 2.4MB
  int* deg    = (int*)w;       w += (size_t)N_NODES * sizeof(int);
  int* cursor = (int*)w;       w += (size_t)N_NODES * sizeof(int);
  int* rowptr = (int*)w;       w += ((size_t)N_NODES + 1) * sizeof(int);

  hipMemsetAsync(out, 0, (size_t)N_GRAPHS * N_LAYERS * HID * sizeof(float), stream);
  hipMemsetAsync(deg, 0, (size_t)N_NODES * sizeof(int), stream);

  scale_kernel<<<(N_NODES * 32 + 255) / 256, 256, 0, stream>>>(x, imp, h);
  hist_kernel<<<(N_EDGES + 255) / 256, 256, 0, stream>>>(dst, deg);
  scan_kernel<<<1, 1024, 0, stream>>>(deg, rowptr, cursor);
  scatter_kernel<<<(N_EDGES + 255) / 256, 256, 0, stream>>>(src, dst, cursor, esrc);

  for (int l = 0; l < N_LAYERS; ++l) {
    aggr_kernel<<<(N_NODES + 3) / 4, 256, 0, stream>>>(h, rowptr, esrc, z);
    mlp_pool_kernel<<<256, 1024, 0, stream>>>(
        z, W1 + (size_t)l * HID * HID, b1 + (size_t)l * HID,
        W2 + (size_t)l * HID * HID, b2 + (size_t)l * HID,
        imp, batch, h, out, l * HID);
  }
}

// Round 4
// 733.392 us; speedup vs baseline: 7.4492x; 7.4492x over previous
//
#include <hip/hip_runtime.h>

#define N_NODES 50000
#define N_EDGES 600000
#define HID 128
#define N_LAYERS 3
#define N_GRAPHS 64
#define DEG_PAD 53248   // 1024 threads * 52 ints (13 int4) >= N_NODES, zero-padded

// ---------------- h = x * node_imp ----------------
__global__ __launch_bounds__(256) void scale_kernel(const float* __restrict__ x,
                                                    const float* __restrict__ imp,
                                                    float* __restrict__ h) {
  int i = blockIdx.x * 256 + threadIdx.x;            // over N_NODES*32 float4
  if (i >= N_NODES * (HID / 4)) return;
  float s = imp[i >> 5];
  float4 v = reinterpret_cast<const float4*>(x)[i];
  v.x *= s; v.y *= s; v.z *= s; v.w *= s;
  reinterpret_cast<float4*>(h)[i] = v;
}

// ---------------- CSR build: histogram ----------------
__global__ __launch_bounds__(256) void hist_kernel(const int* __restrict__ dst,
                                                   int* __restrict__ deg) {
  int e = blockIdx.x * 256 + threadIdx.x;
  if (e < N_EDGES) atomicAdd(&deg[dst[e]], 1);
}

// ---------------- CSR build: exclusive scan (single block, 1024 thr) --------
// 13 independent int4 loads per thread (MLP, no serial dependent chain),
// wave shfl-scan of per-thread sums, second pass entirely from registers.
__global__ __launch_bounds__(1024) void scan_kernel(const int* __restrict__ deg,
                                                    int* __restrict__ rowptr,
                                                    int* __restrict__ cursor) {
  const int tid = threadIdx.x;
  const int lane = tid & 63;
  const int wid = tid >> 6;
  int4 d[13];
  const int4* deg4 = reinterpret_cast<const int4*>(deg);
#pragma unroll
  for (int j = 0; j < 13; ++j) d[j] = deg4[tid * 13 + j];   // independent loads
  int sum = 0;
#pragma unroll
  for (int j = 0; j < 13; ++j) sum += d[j].x + d[j].y + d[j].z + d[j].w;
  int incl = sum;
#pragma unroll
  for (int off = 1; off < 64; off <<= 1) {
    int t = __shfl_up(incl, off, 64);
    if (lane >= off) incl += t;
  }
  __shared__ int wsum[16];
  __shared__ int wpre[16];
  if (lane == 63) wsum[wid] = incl;
  __syncthreads();
  if (tid == 0) {
    int c = 0;
#pragma unroll
    for (int i = 0; i < 16; ++i) { wpre[i] = c; c += wsum[i]; }
  }
  __syncthreads();
  int run = wpre[wid] + incl - sum;                  // block-exclusive prefix
  if (tid == 0) rowptr[0] = 0;
  const int base = tid * 52;
#pragma unroll
  for (int j = 0; j < 13; ++j) {
    int v[4] = {d[j].x, d[j].y, d[j].z, d[j].w};
#pragma unroll
    for (int q = 0; q < 4; ++q) {
      int idx = base + j * 4 + q;
      if (idx < N_NODES) {
        cursor[idx] = run;
        run += v[q];
        rowptr[idx + 1] = run;
      }
    }
  }
}

// ---------------- CSR build: scatter edge sources by dst ----------------
__global__ __launch_bounds__(256) void scatter_kernel(const int* __restrict__ src,
                                                      const int* __restrict__ dst,
                                                      int* __restrict__ cursor,
                                                      int* __restrict__ esrc) {
  int e = blockIdx.x * 256 + threadIdx.x;
  if (e >= N_EDGES) return;
  int pos = atomicAdd(&cursor[dst[e]], 1);
  esrc[pos] = src[e];
}

// ---------------- z = h + sum_{j->i} h[j]  (one wave per node) --------------
__global__ __launch_bounds__(256) void aggr_kernel(const float* __restrict__ h,
                                                   const int* __restrict__ rowptr,
                                                   const int* __restrict__ esrc,
                                                   float* __restrict__ z) {
  int wid = (blockIdx.x * 256 + threadIdx.x) >> 6;   // node id, 1 wave each
  if (wid >= N_NODES) return;
  int lane = threadIdx.x & 63;
  const float2* h2 = reinterpret_cast<const float2*>(h);
  float2 acc = h2[(size_t)wid * 64 + lane];          // self term (eps = 0)
  float2 acc2 = make_float2(0.f, 0.f);
  int s = rowptr[wid], e = rowptr[wid + 1];
  int j = s;
  for (; j + 2 <= e; j += 2) {                       // 2-way MLP unroll
    int s0 = esrc[j], s1 = esrc[j + 1];
    float2 v0 = h2[(size_t)s0 * 64 + lane];
    float2 v1 = h2[(size_t)s1 * 64 + lane];
    acc.x += v0.x; acc.y += v0.y;
    acc2.x += v1.x; acc2.y += v1.y;
  }
  if (j < e) {
    float2 v = h2[(size_t)esrc[j] * 64 + lane];
    acc.x += v.x; acc.y += v.y;
  }
  acc.x += acc2.x; acc.y += acc2.y;
  reinterpret_cast<float2*>(z)[(size_t)wid * 64 + lane] = acc;
}

// ---------------- fused MLP + h-update + pool ----------------
// 1024 thr, __launch_bounds__(1024,4): 1 block/CU, 16 waves (4/SIMD), VGPR<=128.
// Chunk = 128 rows, thread = (rg 0..31)x(fg 0..31), 4 rows x 4 cols each.
// LDS: Ws 64KB (W1 then W2, re-staged from L2-hot global) + zs 64KB (z then t,
// then pool-reduce scratch) = 128KB -> 1 block/CU.
#define GEMM_PASS(ACC, BIAS)                                                   \
  {                                                                            \
    ACC[0] = BIAS; ACC[1] = BIAS; ACC[2] = BIAS; ACC[3] = BIAS;                \
    const float4* Wv = reinterpret_cast<const float4*>(Ws);                    \
    const float4* Zv = reinterpret_cast<const float4*>(zs);                    \
    _Pragma("unroll 4")                                                        \
    for (int k4 = 0; k4 < 32; ++k4) {                                          \
      float4 w0 = Wv[(4 * k4 + 0) * 32 + fg];                                  \
      float4 w1 = Wv[(4 * k4 + 1) * 32 + fg];                                  \
      float4 w2 = Wv[(4 * k4 + 2) * 32 + fg];                                  \
      float4 w3 = Wv[(4 * k4 + 3) * 32 + fg];                                  \
      _Pragma("unroll")                                                        \
      for (int r = 0; r < 4; ++r) {                                            \
        float4 q = Zv[(rg + r * 32) * 32 + k4];                                \
        ACC[r].x += q.x * w0.x + q.y * w1.x + q.z * w2.x + q.w * w3.x;         \
        ACC[r].y += q.x * w0.y + q.y * w1.y + q.z * w2.y + q.w * w3.y;         \
        ACC[r].z += q.x * w0.z + q.y * w1.z + q.z * w2.z + q.w * w3.z;         \
        ACC[r].w += q.x * w0.w + q.y * w1.w + q.z * w2.w + q.w * w3.w;         \
      }                                                                        \
    }                                                                          \
  }

__global__ __launch_bounds__(1024, 4) void mlp_pool_kernel(
    const float* __restrict__ z, const float* __restrict__ W1,
    const float* __restrict__ b1, const float* __restrict__ W2,
    const float* __restrict__ b2, const float* __restrict__ imp,
    const int* __restrict__ batch, float* __restrict__ h,
    float* __restrict__ out, int lofs) {
  __shared__ float Ws[HID * HID];                    // 64KB: W1, then W2
  __shared__ float zs[128 * HID];                    // 64KB: z, then t, then reduce

  const int tid = threadIdx.x;
  const int fg = tid & 31;                           // cols fg*4 .. fg*4+3
  const int rg = tid >> 5;                           // rows rg, rg+32, rg+64, rg+96
  const int row0 = blockIdx.x << 7;                  // 128 rows per block

  {  // stage W1 + z tile
    const float4* wsrc = reinterpret_cast<const float4*>(W1);
    float4* wdst = reinterpret_cast<float4*>(Ws);
#pragma unroll
    for (int i = 0; i < 4; ++i) wdst[tid + i * 1024] = wsrc[tid + i * 1024];
    const float4* zsrc = reinterpret_cast<const float4*>(z);
    float4* zdst = reinterpret_cast<float4*>(zs);
#pragma unroll
    for (int i = 0; i < 4; ++i) {
      int idx = tid + i * 1024;
      int rr = row0 + (idx >> 5);
      zdst[idx] = (rr < N_NODES) ? zsrc[(size_t)rr * 32 + (idx & 31)]
                                 : make_float4(0.f, 0.f, 0.f, 0.f);
    }
  }
  const float4 bias1 = reinterpret_cast<const float4*>(b1)[fg];
  const float4 bias2 = reinterpret_cast<const float4*>(b2)[fg];
  __syncthreads();

  // ---- GEMM1: acc = z @ W1 + b1 ----
  float4 acc[4];
  GEMM_PASS(acc, bias1);
  __syncthreads();                                   // zs + Ws reads done

  {  // t = relu(acc) into zs; re-stage Ws with W2 (L2-hot)
#pragma unroll
    for (int r = 0; r < 4; ++r) {
      float4 t;
      t.x = fmaxf(acc[r].x, 0.f); t.y = fmaxf(acc[r].y, 0.f);
      t.z = fmaxf(acc[r].z, 0.f); t.w = fmaxf(acc[r].w, 0.f);
      reinterpret_cast<float4*>(zs)[(rg + r * 32) * 32 + fg] = t;
    }
    const float4* wsrc = reinterpret_cast<const float4*>(W2);
    float4* wdst = reinterpret_cast<float4*>(Ws);
#pragma unroll
    for (int i = 0; i < 4; ++i) wdst[tid + i * 1024] = wsrc[tid + i * 1024];
  }
  __syncthreads();

  // ---- GEMM2: o_ = t @ W2 + b2 ----
  float4 o_[4];
  GEMM_PASS(o_, bias2);

  // ---- epilogue: h = relu(o_)*imp, write h, pool ----
  float4 psum = make_float4(0.f, 0.f, 0.f, 0.f);
#pragma unroll
  for (int r = 0; r < 4; ++r) {
    int row = row0 + rg + r * 32;
    float si = (row < N_NODES) ? imp[row] : 0.f;     // pad rows contribute 0
    float4 hv;
    hv.x = fmaxf(o_[r].x, 0.f) * si; hv.y = fmaxf(o_[r].y, 0.f) * si;
    hv.z = fmaxf(o_[r].z, 0.f) * si; hv.w = fmaxf(o_[r].w, 0.f) * si;
    if (row < N_NODES)
      reinterpret_cast<float4*>(h)[(size_t)row * 32 + fg] = hv;
    o_[r] = hv;                                      // keep for non-uniform path
    psum.x += hv.x; psum.y += hv.y; psum.z += hv.z; psum.w += hv.w;
  }
  const int rlast = min(row0 + 127, N_NODES - 1);
  const int g0 = batch[row0];
  const bool uniform = (batch[rlast] == g0);         // block-uniform condition
  __syncthreads();                                   // GEMM2 zs reads done

  if (uniform) {
    // tree-reduce 32 rg partials in LDS -> 128 atomics per chunk
    reinterpret_cast<float4*>(zs)[tid] = psum;       // tid = rg*32+fg
    __syncthreads();
#pragma unroll
    for (int st = 16; st >= 1; st >>= 1) {
      if (rg < st) {
        float4 o = reinterpret_cast<const float4*>(zs)[(rg + st) * 32 + fg];
        psum.x += o.x; psum.y += o.y; psum.z += o.z; psum.w += o.w;
        if (st > 1) reinterpret_cast<float4*>(zs)[tid] = psum;
      }
      __syncthreads();
    }
    if (rg == 0) {
      float* op = out + (size_t)g0 * (N_LAYERS * HID) + lofs + fg * 4;
      atomicAdd(op + 0, psum.x); atomicAdd(op + 1, psum.y);
      atomicAdd(op + 2, psum.z); atomicAdd(op + 3, psum.w);
    }
  } else {
    // graph-boundary chunk (~63 of 391): per-row atomics
#pragma unroll
    for (int r = 0; r < 4; ++r) {
      int row = row0 + rg + r * 32;
      if (row < N_NODES) {
        float* op = out + (size_t)batch[row] * (N_LAYERS * HID) + lofs + fg * 4;
        atomicAdd(op + 0, o_[r].x); atomicAdd(op + 1, o_[r].y);
        atomicAdd(op + 2, o_[r].z); atomicAdd(op + 3, o_[r].w);
      }
    }
  }
}

extern "C" void kernel_launch(void* const* d_in, const int* in_sizes, int n_in,
                              void* d_out, int out_size, void* d_ws, size_t ws_size,
                              hipStream_t stream) {
  const float* x    = (const float*)d_in[0];
  const int*   ei   = (const int*)d_in[1];          // [2, N_EDGES]
  const int*   batch= (const int*)d_in[2];
  const float* imp  = (const float*)d_in[3];
  const float* W1   = (const float*)d_in[4];        // [3,128,128]
  const float* b1   = (const float*)d_in[5];        // [3,128]
  const float* W2   = (const float*)d_in[6];
  const float* b2   = (const float*)d_in[7];
  float* out = (float*)d_out;                       // [64, 384]

  const int* src = ei;
  const int* dst = ei + N_EDGES;

  // workspace layout (16B-aligned floats first)
  char* w = (char*)d_ws;
  float* h = (float*)w;        w += (size_t)N_NODES * HID * sizeof(float);   // 25.6MB
  float* z = (float*)w;        w += (size_t)N_NODES * HID * sizeof(float);   // 25.6MB
  int* esrc   = (int*)w;       w += (size_t)N_EDGES * sizeof(int);           // 2.4MB
  int* deg    = (int*)w;       w += (size_t)DEG_PAD * sizeof(int);           // padded
  int* cursor = (int*)w;       w += (size_t)N_NODES * sizeof(int);
  int* rowptr = (int*)w;       w += ((size_t)N_NODES + 1) * sizeof(int);

  hipMemsetAsync(out, 0, (size_t)N_GRAPHS * N_LAYERS * HID * sizeof(float), stream);
  hipMemsetAsync(deg, 0, (size_t)DEG_PAD * sizeof(int), stream);

  scale_kernel<<<(N_NODES * 32 + 255) / 256, 256, 0, stream>>>(x, imp, h);
  hist_kernel<<<(N_EDGES + 255) / 256, 256, 0, stream>>>(dst, deg);
  scan_kernel<<<1, 1024, 0, stream>>>(deg, rowptr, cursor);
  scatter_kernel<<<(N_EDGES + 255) / 256, 256, 0, stream>>>(src, dst, cursor, esrc);

  const int mlp_grid = (N_NODES + 127) / 128;       // 391 chunks
  for (int l = 0; l < N_LAYERS; ++l) {
    aggr_kernel<<<(N_NODES + 3) / 4, 256, 0, stream>>>(h, rowptr, esrc, z);
    mlp_pool_kernel<<<mlp_grid, 1024, 0, stream>>>(
        z, W1 + (size_t)l * HID * HID, b1 + (size_t)l * HID,
        W2 + (size_t)l * HID * HID, b2 + (size_t)l * HID,
        imp, batch, h, out, l * HID);
  }
}

// Round 6
// 406.977 us; speedup vs baseline: 13.4238x; 1.8020x over previous
//
#include <hip/hip_runtime.h>
#include <hip/hip_bf16.h>

#define N_NODES 50000
#define N_EDGES 600000
#define HID 128
#define N_LAYERS 3
#define N_GRAPHS 64
#define DEG_PAD 53248   // 1024 threads * 52 ints (13 int4) >= N_NODES, zero-padded
#define LDK 136         // padded k-stride (bf16 elems): 272B row ≡ 4 banks mod 32

typedef __attribute__((ext_vector_type(8))) short bf16x8;        // MFMA A/B frag
typedef __attribute__((ext_vector_type(8))) unsigned short u16x8; // staging loads
typedef __attribute__((ext_vector_type(4))) float f32x4;         // MFMA C/D frag

__device__ __forceinline__ unsigned short f2bf(float v) {
  __hip_bfloat16 b = __float2bfloat16(v);   // RNE
  unsigned short u;
  __builtin_memcpy(&u, &b, 2);
  return u;
}

// ---------------- h = x * node_imp ----------------
__global__ __launch_bounds__(256) void scale_kernel(const float* __restrict__ x,
                                                    const float* __restrict__ imp,
                                                    float* __restrict__ h) {
  int i = blockIdx.x * 256 + threadIdx.x;            // over N_NODES*32 float4
  if (i >= N_NODES * (HID / 4)) return;
  float s = imp[i >> 5];
  float4 v = reinterpret_cast<const float4*>(x)[i];
  v.x *= s; v.y *= s; v.z *= s; v.w *= s;
  reinterpret_cast<float4*>(h)[i] = v;
}

// ---------------- W pre-convert: f32 [k][n] -> bf16 Wt [n][k] ----------------
__global__ __launch_bounds__(256) void wconv_kernel(const float* __restrict__ W1,
                                                    const float* __restrict__ W2,
                                                    unsigned short* __restrict__ wt) {
  const int m = blockIdx.x;                          // 0..5
  const float* src = (m < 3) ? (W1 + (size_t)m * HID * HID)
                             : (W2 + (size_t)(m - 3) * HID * HID);
  unsigned short* dst = wt + (size_t)m * HID * HID;
  const int tid = threadIdx.x;
  const int n = tid >> 1, kh = (tid & 1) * 64;
#pragma unroll 8
  for (int k = 0; k < 64; ++k)
    dst[n * HID + kh + k] = f2bf(src[(kh + k) * HID + n]);
}

// ---------------- CSR build: histogram ----------------
__global__ __launch_bounds__(256) void hist_kernel(const int* __restrict__ dst,
                                                   int* __restrict__ deg) {
  int e = blockIdx.x * 256 + threadIdx.x;
  if (e < N_EDGES) atomicAdd(&deg[dst[e]], 1);
}

// ---------------- CSR build: exclusive scan (single block, 1024 thr) --------
__global__ __launch_bounds__(1024) void scan_kernel(const int* __restrict__ deg,
                                                    int* __restrict__ rowptr,
                                                    int* __restrict__ cursor) {
  const int tid = threadIdx.x;
  const int lane = tid & 63;
  const int wid = tid >> 6;
  int4 d[13];
  const int4* deg4 = reinterpret_cast<const int4*>(deg);
#pragma unroll
  for (int j = 0; j < 13; ++j) d[j] = deg4[tid * 13 + j];   // independent loads
  int sum = 0;
#pragma unroll
  for (int j = 0; j < 13; ++j) sum += d[j].x + d[j].y + d[j].z + d[j].w;
  int incl = sum;
#pragma unroll
  for (int off = 1; off < 64; off <<= 1) {
    int t = __shfl_up(incl, off, 64);
    if (lane >= off) incl += t;
  }
  __shared__ int wsum[16];
  __shared__ int wpre[16];
  if (lane == 63) wsum[wid] = incl;
  __syncthreads();
  if (tid == 0) {
    int c = 0;
#pragma unroll
    for (int i = 0; i < 16; ++i) { wpre[i] = c; c += wsum[i]; }
  }
  __syncthreads();
  int run = wpre[wid] + incl - sum;                  // block-exclusive prefix
  if (tid == 0) rowptr[0] = 0;
  const int base = tid * 52;
#pragma unroll
  for (int j = 0; j < 13; ++j) {
    int v[4] = {d[j].x, d[j].y, d[j].z, d[j].w};
#pragma unroll
    for (int q = 0; q < 4; ++q) {
      int idx = base + j * 4 + q;
      if (idx < N_NODES) {
        cursor[idx] = run;
        run += v[q];
        rowptr[idx + 1] = run;
      }
    }
  }
}

// ---------------- CSR build: scatter edge sources by dst ----------------
__global__ __launch_bounds__(256) void scatter_kernel(const int* __restrict__ src,
                                                      const int* __restrict__ dst,
                                                      int* __restrict__ cursor,
                                                      int* __restrict__ esrc) {
  int e = blockIdx.x * 256 + threadIdx.x;
  if (e >= N_EDGES) return;
  int pos = atomicAdd(&cursor[dst[e]], 1);
  esrc[pos] = src[e];
}

// -------- z = h + sum_{j->i} h[j]  (one wave per node, bf16 output) --------
__global__ __launch_bounds__(256) void aggr_kernel(const float* __restrict__ h,
                                                   const int* __restrict__ rowptr,
                                                   const int* __restrict__ esrc,
                                                   unsigned int* __restrict__ zb) {
  int wid = (blockIdx.x * 256 + threadIdx.x) >> 6;   // node id, 1 wave each
  if (wid >= N_NODES) return;
  int lane = threadIdx.x & 63;
  const float2* h2 = reinterpret_cast<const float2*>(h);
  float2 acc = h2[(size_t)wid * 64 + lane];          // self term (eps = 0)
  float2 acc2 = make_float2(0.f, 0.f);
  int s = rowptr[wid], e = rowptr[wid + 1];
  int j = s;
  for (; j + 2 <= e; j += 2) {                       // 2-way MLP unroll
    int s0 = esrc[j], s1 = esrc[j + 1];
    float2 v0 = h2[(size_t)s0 * 64 + lane];
    float2 v1 = h2[(size_t)s1 * 64 + lane];
    acc.x += v0.x; acc.y += v0.y;
    acc2.x += v1.x; acc2.y += v1.y;
  }
  if (j < e) {
    float2 v = h2[(size_t)esrc[j] * 64 + lane];
    acc.x += v.x; acc.y += v.y;
  }
  acc.x += acc2.x; acc.y += acc2.y;
  unsigned int lo = f2bf(acc.x), hi = f2bf(acc.y);
  zb[(size_t)wid * 64 + lane] = lo | (hi << 16);     // 2 bf16 packed
}

// ---------------- fused MFMA MLP + h-update + pool ----------------
// 512 thr = 8 waves; chunk = 128 rows; wave w owns rows [w*16, w*16+16).
// GEMM: mfma_f32_16x16x32_bf16, 8 col-tiles x 4 k-steps per wave per GEMM.
// LDS: Wbuf[128][136]bf16 (Wt1 then Wt2) + Zbuf[128][136]bf16 (z then t)
//      + pool[128]f32 = 68.5KB -> 2 blocks/CU (__launch_bounds__(512,4)).
// Staging decomposition: 128 rows x 16 u16x8-chunks/row -> r = g>>4, kc = g&15.
// (R5 bug: g>>3/g&7 -> OOB LDS writes -> inf.)
__global__ __launch_bounds__(512, 4) void mlp_pool_kernel(
    const unsigned int* __restrict__ zb, const unsigned short* __restrict__ wt1,
    const float* __restrict__ b1, const unsigned short* __restrict__ wt2,
    const float* __restrict__ b2, const float* __restrict__ imp,
    const int* __restrict__ batch, float* __restrict__ h,
    float* __restrict__ out, int lofs) {
  __shared__ unsigned short Wbuf[128 * LDK];
  __shared__ unsigned short Zbuf[128 * LDK];
  __shared__ float pool_shf[HID];

  const int tid = threadIdx.x;
  const int lane = tid & 63;
  const int l15 = lane & 15, lg = lane >> 4;
  const int wrow0 = (tid >> 6) * 16;                 // wave's 16-row stripe
  const int row0 = blockIdx.x << 7;                  // chunk base

  {  // stage Wt1 + z tile (bf16, 16B chunks)
    const u16x8* wsrc = reinterpret_cast<const u16x8*>(wt1);
    const u16x8* zsrc = reinterpret_cast<const u16x8*>(zb);
#pragma unroll
    for (int i = 0; i < 4; ++i) {
      int g = tid + i * 512;                         // 2048 chunks of 8 bf16
      int r = g >> 4, kc = g & 15;                   // 16 chunks per 128-elem row
      *reinterpret_cast<u16x8*>(&Wbuf[r * LDK + kc * 8]) = wsrc[g];
      u16x8 zv = {0, 0, 0, 0, 0, 0, 0, 0};
      if (row0 + r < N_NODES) zv = zsrc[(size_t)(row0 + r) * 16 + kc];
      *reinterpret_cast<u16x8*>(&Zbuf[r * LDK + kc * 8]) = zv;
    }
  }
  float b1g[8], b2g[8];
#pragma unroll
  for (int ct = 0; ct < 8; ++ct) b1g[ct] = b1[ct * 16 + l15];
  __syncthreads();

  // ---- GEMM1: acc = z @ W1 ----
  bf16x8 a[4];
#pragma unroll
  for (int ks = 0; ks < 4; ++ks)
    a[ks] = *reinterpret_cast<const bf16x8*>(&Zbuf[(wrow0 + l15) * LDK + ks * 32 + lg * 8]);
  f32x4 acc[8];
#pragma unroll
  for (int ct = 0; ct < 8; ++ct) {
    acc[ct] = (f32x4){0.f, 0.f, 0.f, 0.f};
#pragma unroll
    for (int ks = 0; ks < 4; ++ks) {
      bf16x8 b = *reinterpret_cast<const bf16x8*>(
          &Wbuf[(ct * 16 + l15) * LDK + ks * 32 + lg * 8]);
      acc[ct] = __builtin_amdgcn_mfma_f32_16x16x32_bf16(a[ks], b, acc[ct], 0, 0, 0);
    }
  }

  // t = relu(acc+b1) -> Zbuf (bf16). Wave-private rows: no barrier needed here.
#pragma unroll
  for (int ct = 0; ct < 8; ++ct) {
#pragma unroll
    for (int r = 0; r < 4; ++r) {
      float v = fmaxf(acc[ct][r] + b1g[ct], 0.f);
      Zbuf[(wrow0 + lg * 4 + r) * LDK + ct * 16 + l15] = f2bf(v);
    }
  }
  __syncthreads();                                   // all GEMM1 Wbuf reads done

  {  // re-stage Wbuf with Wt2; zero pool accumulator
    const u16x8* wsrc = reinterpret_cast<const u16x8*>(wt2);
#pragma unroll
    for (int i = 0; i < 4; ++i) {
      int g = tid + i * 512;
      *reinterpret_cast<u16x8*>(&Wbuf[(g >> 4) * LDK + (g & 15) * 8]) = wsrc[g];
    }
    if (tid < HID) pool_shf[tid] = 0.f;
#pragma unroll
    for (int ct = 0; ct < 8; ++ct) b2g[ct] = b2[ct * 16 + l15];
  }
  __syncthreads();

  // ---- GEMM2: acc = t @ W2 ----
#pragma unroll
  for (int ks = 0; ks < 4; ++ks)
    a[ks] = *reinterpret_cast<const bf16x8*>(&Zbuf[(wrow0 + l15) * LDK + ks * 32 + lg * 8]);
#pragma unroll
  for (int ct = 0; ct < 8; ++ct) {
    acc[ct] = (f32x4){0.f, 0.f, 0.f, 0.f};
#pragma unroll
    for (int ks = 0; ks < 4; ++ks) {
      bf16x8 b = *reinterpret_cast<const bf16x8*>(
          &Wbuf[(ct * 16 + l15) * LDK + ks * 32 + lg * 8]);
      acc[ct] = __builtin_amdgcn_mfma_f32_16x16x32_bf16(a[ks], b, acc[ct], 0, 0, 0);
    }
  }

  // ---- epilogue: h = relu(acc+b2)*imp (in place), store h, pool ----
  float impv[4];
  int glane[4];
#pragma unroll
  for (int r = 0; r < 4; ++r) {
    int row = row0 + wrow0 + lg * 4 + r;
    bool ok = row < N_NODES;
    impv[r] = ok ? imp[row] : 0.f;
    glane[r] = ok ? batch[row] : -1;
  }
#pragma unroll
  for (int ct = 0; ct < 8; ++ct) {
#pragma unroll
    for (int r = 0; r < 4; ++r) {
      float hv = fmaxf(acc[ct][r] + b2g[ct], 0.f) * impv[r];
      acc[ct][r] = hv;
      int row = row0 + wrow0 + lg * 4 + r;
      if (row < N_NODES) h[(size_t)row * HID + ct * 16 + l15] = hv;
    }
  }
  const int rlast = min(row0 + 127, N_NODES - 1);
  const int g0 = batch[row0];
  const bool uniform = (batch[rlast] == g0);         // block-uniform predicate

  if (uniform) {
#pragma unroll
    for (int ct = 0; ct < 8; ++ct) {
      float val = acc[ct][0] + acc[ct][1] + acc[ct][2] + acc[ct][3];
      val += __shfl_xor(val, 16, 64);                // combine 4 lane-groups
      val += __shfl_xor(val, 32, 64);
      if (lane < 16) atomicAdd(&pool_shf[ct * 16 + l15], val);
    }
  } else {
    const int glast = batch[rlast];
    for (int g = g0; g <= glast; ++g) {              // few graphs per boundary chunk
#pragma unroll
      for (int ct = 0; ct < 8; ++ct) {
        float val = 0.f;
#pragma unroll
        for (int r = 0; r < 4; ++r)
          if (glane[r] == g) val += acc[ct][r];
        val += __shfl_xor(val, 16, 64);
        val += __shfl_xor(val, 32, 64);
        if (lane < 16)
          atomicAdd(out + (size_t)g * (N_LAYERS * HID) + lofs + ct * 16 + l15, val);
      }
    }
  }
  __syncthreads();
  if (uniform && tid < HID)
    atomicAdd(out + (size_t)g0 * (N_LAYERS * HID) + lofs + tid, pool_shf[tid]);
}

extern "C" void kernel_launch(void* const* d_in, const int* in_sizes, int n_in,
                              void* d_out, int out_size, void* d_ws, size_t ws_size,
                              hipStream_t stream) {
  const float* x    = (const float*)d_in[0];
  const int*   ei   = (const int*)d_in[1];          // [2, N_EDGES]
  const int*   batch= (const int*)d_in[2];
  const float* imp  = (const float*)d_in[3];
  const float* W1   = (const float*)d_in[4];        // [3,128,128]
  const float* b1   = (const float*)d_in[5];        // [3,128]
  const float* W2   = (const float*)d_in[6];
  const float* b2   = (const float*)d_in[7];
  float* out = (float*)d_out;                       // [64, 384]

  const int* src = ei;
  const int* dst = ei + N_EDGES;

  // workspace layout (16B-aligned)
  char* w = (char*)d_ws;
  float* h = (float*)w;             w += (size_t)N_NODES * HID * sizeof(float);     // 25.6MB
  unsigned int* zb = (unsigned int*)w; w += (size_t)N_NODES * (HID / 2) * sizeof(int); // 12.8MB bf16
  unsigned short* wt = (unsigned short*)w; w += (size_t)6 * HID * HID * sizeof(short); // 196KB
  int* esrc   = (int*)w;            w += (size_t)N_EDGES * sizeof(int);             // 2.4MB
  int* deg    = (int*)w;            w += (size_t)DEG_PAD * sizeof(int);
  int* cursor = (int*)w;            w += (size_t)N_NODES * sizeof(int);
  int* rowptr = (int*)w;            w += ((size_t)N_NODES + 1) * sizeof(int);

  hipMemsetAsync(out, 0, (size_t)N_GRAPHS * N_LAYERS * HID * sizeof(float), stream);
  hipMemsetAsync(deg, 0, (size_t)DEG_PAD * sizeof(int), stream);

  scale_kernel<<<(N_NODES * 32 + 255) / 256, 256, 0, stream>>>(x, imp, h);
  wconv_kernel<<<6, 256, 0, stream>>>(W1, W2, wt);
  hist_kernel<<<(N_EDGES + 255) / 256, 256, 0, stream>>>(dst, deg);
  scan_kernel<<<1, 1024, 0, stream>>>(deg, rowptr, cursor);
  scatter_kernel<<<(N_EDGES + 255) / 256, 256, 0, stream>>>(src, dst, cursor, esrc);

  const int mlp_grid = (N_NODES + 127) / 128;       // 391 chunks
  for (int l = 0; l < N_LAYERS; ++l) {
    aggr_kernel<<<(N_NODES + 3) / 4, 256, 0, stream>>>(h, rowptr, esrc, zb);
    mlp_pool_kernel<<<mlp_grid, 512, 0, stream>>>(
        zb, wt + (size_t)l * HID * HID, b1 + (size_t)l * HID,
        wt + (size_t)(3 + l) * HID * HID, b2 + (size_t)l * HID,
        imp, batch, h, out, l * HID);
  }
}

// Round 7
// 339.392 us; speedup vs baseline: 16.0969x; 1.1991x over previous
//
#include <hip/hip_runtime.h>
#include <hip/hip_bf16.h>

#define N_NODES 50000
#define N_EDGES 600000
#define HID 128
#define N_LAYERS 3
#define N_GRAPHS 64
#define DEG_PAD 53248       // 52 blocks * 256 thr * 4 ints, zero-padded
#define SCAN_BLOCKS 52
#define LDK 136             // padded k-stride (bf16): 272B row ≡ 4 banks mod 32

typedef __attribute__((ext_vector_type(8))) short bf16x8;        // MFMA A/B frag
typedef __attribute__((ext_vector_type(8))) unsigned short u16x8; // 16B chunks
typedef __attribute__((ext_vector_type(4))) float f32x4;         // MFMA C/D frag

__device__ __forceinline__ unsigned short f2bf(float v) {
  __hip_bfloat16 b = __float2bfloat16(v);   // RNE
  unsigned short u;
  __builtin_memcpy(&u, &b, 2);
  return u;
}
__device__ __forceinline__ float bflo(unsigned int v) {
  unsigned int u = v << 16; float f; __builtin_memcpy(&f, &u, 4); return f;
}
__device__ __forceinline__ float bfhi(unsigned int v) {
  unsigned int u = v & 0xFFFF0000u; float f; __builtin_memcpy(&f, &u, 4); return f;
}

// ---------------- hb = bf16(x * node_imp), packed 2/uint ----------------
__global__ __launch_bounds__(256) void scale_kernel(const float* __restrict__ x,
                                                    const float* __restrict__ imp,
                                                    unsigned int* __restrict__ hb) {
  int i = blockIdx.x * 256 + threadIdx.x;            // over N_NODES*32 float4
  if (i >= N_NODES * (HID / 4)) return;
  float s = imp[i >> 5];
  float4 v = reinterpret_cast<const float4*>(x)[i];
  uint2 p;
  p.x = (unsigned)f2bf(v.x * s) | ((unsigned)f2bf(v.y * s) << 16);
  p.y = (unsigned)f2bf(v.z * s) | ((unsigned)f2bf(v.w * s) << 16);
  reinterpret_cast<uint2*>(hb)[i] = p;
}

// ---------------- W pre-convert: f32 [k][n] -> bf16 Wt [n][k] ----------------
__global__ __launch_bounds__(256) void wconv_kernel(const float* __restrict__ W1,
                                                    const float* __restrict__ W2,
                                                    unsigned short* __restrict__ wt) {
  const int m = blockIdx.x;                          // 0..5
  const float* src = (m < 3) ? (W1 + (size_t)m * HID * HID)
                             : (W2 + (size_t)(m - 3) * HID * HID);
  unsigned short* dst = wt + (size_t)m * HID * HID;
  const int tid = threadIdx.x;
  const int n = tid >> 1, kh = (tid & 1) * 64;
#pragma unroll 8
  for (int k = 0; k < 64; ++k)
    dst[n * HID + kh + k] = f2bf(src[(kh + k) * HID + n]);
}

// ---------------- CSR build: histogram ----------------
__global__ __launch_bounds__(256) void hist_kernel(const int* __restrict__ dst,
                                                   int* __restrict__ deg) {
  int e = blockIdx.x * 256 + threadIdx.x;
  if (e < N_EDGES) atomicAdd(&deg[dst[e]], 1);
}

// ------------- CSR scan, 3-kernel hierarchical (coalesced int4) -------------
__global__ __launch_bounds__(256) void scan1_kernel(const int* __restrict__ deg,
                                                    int* __restrict__ bsum) {
  int t = blockIdx.x * 256 + threadIdx.x;
  int4 d = reinterpret_cast<const int4*>(deg)[t];
  int s = d.x + d.y + d.z + d.w;
#pragma unroll
  for (int off = 1; off < 64; off <<= 1) s += __shfl_xor(s, off, 64);
  __shared__ int ws[4];
  if ((threadIdx.x & 63) == 0) ws[threadIdx.x >> 6] = s;
  __syncthreads();
  if (threadIdx.x == 0) bsum[blockIdx.x] = ws[0] + ws[1] + ws[2] + ws[3];
}

__global__ __launch_bounds__(64) void scan2_kernel(const int* __restrict__ bsum,
                                                   int* __restrict__ boff) {
  int t = threadIdx.x;                               // one wave
  int v = (t < SCAN_BLOCKS) ? bsum[t] : 0;
  int incl = v;
#pragma unroll
  for (int off = 1; off < 64; off <<= 1) {
    int u = __shfl_up(incl, off, 64);
    if (t >= off) incl += u;
  }
  if (t < SCAN_BLOCKS) boff[t] = incl - v;           // exclusive
}

__global__ __launch_bounds__(256) void scan3_kernel(const int* __restrict__ deg,
                                                    const int* __restrict__ boff,
                                                    int* __restrict__ rowptr,
                                                    int* __restrict__ cursor) {
  const int t = blockIdx.x * 256 + threadIdx.x;
  const int lane = threadIdx.x & 63, wid = threadIdx.x >> 6;
  int4 d = reinterpret_cast<const int4*>(deg)[t];
  int tsum = d.x + d.y + d.z + d.w;
  int incl = tsum;
#pragma unroll
  for (int off = 1; off < 64; off <<= 1) {
    int u = __shfl_up(incl, off, 64);
    if (lane >= off) incl += u;
  }
  __shared__ int wsum[4], wpre[4];
  if (lane == 63) wsum[wid] = incl;
  __syncthreads();
  if (threadIdx.x == 0) {
    int c = 0;
#pragma unroll
    for (int i = 0; i < 4; ++i) { wpre[i] = c; c += wsum[i]; }
  }
  __syncthreads();
  int run = boff[blockIdx.x] + wpre[wid] + (incl - tsum);
  int e1 = run + d.x, e2 = e1 + d.y, e3 = e2 + d.z, e4 = e3 + d.w;
  int base = t * 4;                                  // N_NODES % 4 == 0
  if (base < N_NODES) {
    reinterpret_cast<int4*>(cursor)[t] = make_int4(run, e1, e2, e3);
    rowptr[base + 1] = e1; rowptr[base + 2] = e2;
    rowptr[base + 3] = e3; rowptr[base + 4] = e4;
  }
  if (t == 0) rowptr[0] = 0;
}

// ---------------- CSR build: scatter edge sources by dst ----------------
__global__ __launch_bounds__(256) void scatter_kernel(const int* __restrict__ src,
                                                      const int* __restrict__ dst,
                                                      int* __restrict__ cursor,
                                                      int* __restrict__ esrc) {
  int e = blockIdx.x * 256 + threadIdx.x;
  if (e >= N_EDGES) return;
  int pos = atomicAdd(&cursor[dst[e]], 1);
  esrc[pos] = src[e];
}

// ---- z = h + sum_{j->i} h[j]; bf16 h rows (256B), f32 accum, bf16 z ----
__global__ __launch_bounds__(256) void aggr_kernel(const unsigned int* __restrict__ hb,
                                                   const int* __restrict__ rowptr,
                                                   const int* __restrict__ esrc,
                                                   unsigned int* __restrict__ zb) {
  int wid = (blockIdx.x * 256 + threadIdx.x) >> 6;   // node id, 1 wave each
  if (wid >= N_NODES) return;
  int lane = threadIdx.x & 63;
  unsigned int self = hb[(size_t)wid * 64 + lane];
  float accx = bflo(self), accy = bfhi(self);        // self term (eps = 0)
  float a2x = 0.f, a2y = 0.f;
  int s = rowptr[wid], e = rowptr[wid + 1];
  int j = s;
  for (; j + 2 <= e; j += 2) {                       // 2-way MLP unroll
    unsigned int v0 = hb[(size_t)esrc[j] * 64 + lane];
    unsigned int v1 = hb[(size_t)esrc[j + 1] * 64 + lane];
    accx += bflo(v0); accy += bfhi(v0);
    a2x += bflo(v1);  a2y += bfhi(v1);
  }
  if (j < e) {
    unsigned int v = hb[(size_t)esrc[j] * 64 + lane];
    accx += bflo(v); accy += bfhi(v);
  }
  accx += a2x; accy += a2y;
  zb[(size_t)wid * 64 + lane] =
      (unsigned)f2bf(accx) | ((unsigned)f2bf(accy) << 16);
}

// ---------------- fused MFMA MLP + h-update + pool ----------------
// 512 thr = 8 waves; chunk = 128 rows; wave w owns rows [w*16, w*16+16).
// GEMM: mfma_f32_16x16x32_bf16, 8 col-tiles x 4 k-steps per wave per GEMM.
// h output: hv -> Zbuf (bf16, wave-private rows) -> coalesced 16B global.
__global__ __launch_bounds__(512, 4) void mlp_pool_kernel(
    const unsigned int* __restrict__ zb, const unsigned short* __restrict__ wt1,
    const float* __restrict__ b1, const unsigned short* __restrict__ wt2,
    const float* __restrict__ b2, const float* __restrict__ imp,
    const int* __restrict__ batch, u16x8* __restrict__ hb,
    float* __restrict__ out, int lofs) {
  __shared__ unsigned short Wbuf[128 * LDK];
  __shared__ unsigned short Zbuf[128 * LDK];
  __shared__ float pool_shf[HID];

  const int tid = threadIdx.x;
  const int lane = tid & 63;
  const int l15 = lane & 15, lg = lane >> 4;
  const int wrow0 = (tid >> 6) * 16;                 // wave's 16-row stripe
  const int row0 = blockIdx.x << 7;                  // chunk base

  {  // stage Wt1 + z tile (bf16, 16B chunks; 16 chunks per 128-elem row)
    const u16x8* wsrc = reinterpret_cast<const u16x8*>(wt1);
    const u16x8* zsrc = reinterpret_cast<const u16x8*>(zb);
#pragma unroll
    for (int i = 0; i < 4; ++i) {
      int g = tid + i * 512;                         // 2048 chunks
      int r = g >> 4, kc = g & 15;
      *reinterpret_cast<u16x8*>(&Wbuf[r * LDK + kc * 8]) = wsrc[g];
      u16x8 zv = {0, 0, 0, 0, 0, 0, 0, 0};
      if (row0 + r < N_NODES) zv = zsrc[(size_t)(row0 + r) * 16 + kc];
      *reinterpret_cast<u16x8*>(&Zbuf[r * LDK + kc * 8]) = zv;
    }
  }
  float b1g[8], b2g[8];
#pragma unroll
  for (int ct = 0; ct < 8; ++ct) b1g[ct] = b1[ct * 16 + l15];
  __syncthreads();

  // ---- GEMM1: acc = z @ W1 ----
  bf16x8 a[4];
#pragma unroll
  for (int ks = 0; ks < 4; ++ks)
    a[ks] = *reinterpret_cast<const bf16x8*>(&Zbuf[(wrow0 + l15) * LDK + ks * 32 + lg * 8]);
  f32x4 acc[8];
#pragma unroll
  for (int ct = 0; ct < 8; ++ct) {
    acc[ct] = (f32x4){0.f, 0.f, 0.f, 0.f};
#pragma unroll
    for (int ks = 0; ks < 4; ++ks) {
      bf16x8 b = *reinterpret_cast<const bf16x8*>(
          &Wbuf[(ct * 16 + l15) * LDK + ks * 32 + lg * 8]);
      acc[ct] = __builtin_amdgcn_mfma_f32_16x16x32_bf16(a[ks], b, acc[ct], 0, 0, 0);
    }
  }

  // t = relu(acc+b1) -> Zbuf (bf16). Wave-private rows: no barrier needed.
#pragma unroll
  for (int ct = 0; ct < 8; ++ct) {
#pragma unroll
    for (int r = 0; r < 4; ++r) {
      float v = fmaxf(acc[ct][r] + b1g[ct], 0.f);
      Zbuf[(wrow0 + lg * 4 + r) * LDK + ct * 16 + l15] = f2bf(v);
    }
  }
  __syncthreads();                                   // all GEMM1 Wbuf reads done

  {  // re-stage Wbuf with Wt2; zero pool accumulator
    const u16x8* wsrc = reinterpret_cast<const u16x8*>(wt2);
#pragma unroll
    for (int i = 0; i < 4; ++i) {
      int g = tid + i * 512;
      *reinterpret_cast<u16x8*>(&Wbuf[(g >> 4) * LDK + (g & 15) * 8]) = wsrc[g];
    }
    if (tid < HID) pool_shf[tid] = 0.f;
#pragma unroll
    for (int ct = 0; ct < 8; ++ct) b2g[ct] = b2[ct * 16 + l15];
  }
  __syncthreads();

  // ---- GEMM2: acc = t @ W2 ----
#pragma unroll
  for (int ks = 0; ks < 4; ++ks)
    a[ks] = *reinterpret_cast<const bf16x8*>(&Zbuf[(wrow0 + l15) * LDK + ks * 32 + lg * 8]);
#pragma unroll
  for (int ct = 0; ct < 8; ++ct) {
    acc[ct] = (f32x4){0.f, 0.f, 0.f, 0.f};
#pragma unroll
    for (int ks = 0; ks < 4; ++ks) {
      bf16x8 b = *reinterpret_cast<const bf16x8*>(
          &Wbuf[(ct * 16 + l15) * LDK + ks * 32 + lg * 8]);
      acc[ct] = __builtin_amdgcn_mfma_f32_16x16x32_bf16(a[ks], b, acc[ct], 0, 0, 0);
    }
  }

  // ---- epilogue: hv = relu(acc+b2)*imp; hv -> Zbuf bf16; pool from regs ----
  float impv[4];
  int glane[4];
#pragma unroll
  for (int r = 0; r < 4; ++r) {
    int row = row0 + wrow0 + lg * 4 + r;
    bool ok = row < N_NODES;
    impv[r] = ok ? imp[row] : 0.f;
    glane[r] = ok ? batch[row] : -1;
  }
#pragma unroll
  for (int ct = 0; ct < 8; ++ct) {
#pragma unroll
    for (int r = 0; r < 4; ++r) {
      float hv = fmaxf(acc[ct][r] + b2g[ct], 0.f) * impv[r];
      acc[ct][r] = hv;
      // wave-private row: GEMM2 A-frags for this stripe already in registers
      Zbuf[(wrow0 + lg * 4 + r) * LDK + ct * 16 + l15] = f2bf(hv);
    }
  }
  const int rlast = min(row0 + 127, N_NODES - 1);
  const int g0 = batch[row0];
  const bool uniform = (batch[rlast] == g0);         // block-uniform predicate

  if (uniform) {
#pragma unroll
    for (int ct = 0; ct < 8; ++ct) {
      float val = acc[ct][0] + acc[ct][1] + acc[ct][2] + acc[ct][3];
      val += __shfl_xor(val, 16, 64);                // combine 4 lane-groups
      val += __shfl_xor(val, 32, 64);
      if (lane < 16) atomicAdd(&pool_shf[ct * 16 + l15], val);
    }
  } else {
    const int glast = batch[rlast];
    for (int g = g0; g <= glast; ++g) {              // few graphs per boundary chunk
#pragma unroll
      for (int ct = 0; ct < 8; ++ct) {
        float val = 0.f;
#pragma unroll
        for (int r = 0; r < 4; ++r)
          if (glane[r] == g) val += acc[ct][r];
        val += __shfl_xor(val, 16, 64);
        val += __shfl_xor(val, 32, 64);
        if (lane < 16)
          atomicAdd(out + (size_t)g * (N_LAYERS * HID) + lofs + ct * 16 + l15, val);
      }
    }
  }
  __syncthreads();                                   // h in Zbuf + pool_shf ready

  {  // coalesced bf16 h store (16B per thread-chunk)
#pragma unroll
    for (int i = 0; i < 4; ++i) {
      int g = tid + i * 512;
      int r = g >> 4, kc = g & 15;
      if (row0 + r < N_NODES)
        hb[(size_t)(row0 + r) * 16 + kc] =
            *reinterpret_cast<const u16x8*>(&Zbuf[r * LDK + kc * 8]);
    }
  }
  if (uniform && tid < HID)
    atomicAdd(out + (size_t)g0 * (N_LAYERS * HID) + lofs + tid, pool_shf[tid]);
}

extern "C" void kernel_launch(void* const* d_in, const int* in_sizes, int n_in,
                              void* d_out, int out_size, void* d_ws, size_t ws_size,
                              hipStream_t stream) {
  const float* x    = (const float*)d_in[0];
  const int*   ei   = (const int*)d_in[1];          // [2, N_EDGES]
  const int*   batch= (const int*)d_in[2];
  const float* imp  = (const float*)d_in[3];
  const float* W1   = (const float*)d_in[4];        // [3,128,128]
  const float* b1   = (const float*)d_in[5];        // [3,128]
  const float* W2   = (const float*)d_in[6];
  const float* b2   = (const float*)d_in[7];
  float* out = (float*)d_out;                       // [64, 384]

  const int* src = ei;
  const int* dst = ei + N_EDGES;

  // workspace layout (all 16B-aligned)
  char* w = (char*)d_ws;
  unsigned int* hb = (unsigned int*)w; w += (size_t)N_NODES * 64 * sizeof(int);   // 12.8MB bf16
  unsigned int* zb = (unsigned int*)w; w += (size_t)N_NODES * 64 * sizeof(int);   // 12.8MB bf16
  unsigned short* wt = (unsigned short*)w; w += (size_t)6 * HID * HID * sizeof(short); // 196KB
  int* esrc   = (int*)w;            w += (size_t)N_EDGES * sizeof(int);           // 2.4MB
  int* deg    = (int*)w;            w += (size_t)DEG_PAD * sizeof(int);
  int* bsum   = (int*)w;            w += 64 * sizeof(int);
  int* boff   = (int*)w;            w += 64 * sizeof(int);
  int* cursor = (int*)w;            w += (size_t)N_NODES * sizeof(int);
  int* rowptr = (int*)w;            w += ((size_t)N_NODES + 1) * sizeof(int);

  hipMemsetAsync(out, 0, (size_t)N_GRAPHS * N_LAYERS * HID * sizeof(float), stream);
  hipMemsetAsync(deg, 0, (size_t)DEG_PAD * sizeof(int), stream);

  scale_kernel<<<(N_NODES * 32 + 255) / 256, 256, 0, stream>>>(x, imp, hb);
  wconv_kernel<<<6, 256, 0, stream>>>(W1, W2, wt);
  hist_kernel<<<(N_EDGES + 255) / 256, 256, 0, stream>>>(dst, deg);
  scan1_kernel<<<SCAN_BLOCKS, 256, 0, stream>>>(deg, bsum);
  scan2_kernel<<<1, 64, 0, stream>>>(bsum, boff);
  scan3_kernel<<<SCAN_BLOCKS, 256, 0, stream>>>(deg, boff, rowptr, cursor);
  scatter_kernel<<<(N_EDGES + 255) / 256, 256, 0, stream>>>(src, dst, cursor, esrc);

  const int mlp_grid = (N_NODES + 127) / 128;       // 391 chunks
  for (int l = 0; l < N_LAYERS; ++l) {
    aggr_kernel<<<(N_NODES + 3) / 4, 256, 0, stream>>>(hb, rowptr, esrc, zb);
    mlp_pool_kernel<<<mlp_grid, 512, 0, stream>>>(
        zb, wt + (size_t)l * HID * HID, b1 + (size_t)l * HID,
        wt + (size_t)(3 + l) * HID * HID, b2 + (size_t)l * HID,
        imp, batch, (u16x8*)hb, out, l * HID);
  }
}